// Round 6
// baseline (190.994 us; speedup 1.0000x reference)
//
#include <hip/hip_runtime.h>
#include <hip/hip_bf16.h>

#define NDIM 2
#define BB 10
#define H 128
#define PAIRS 90
#define MROWS 128
#define LDH 132      // h0/h1 stride (shorts): 264B. 66 dwords/row ≡ 2 mod 32 -> ≤2-way banks; rows 8B-aligned (b64 ops only!)
#define UST 136      // u/w bf16 stride (shorts): 272B, 16B-aligned rows (b128 reads)
#define LOG2E 1.4426950408889634f
#define LN2   0.6931471805599453f

typedef short short8 __attribute__((ext_vector_type(8)));
typedef short short4v __attribute__((ext_vector_type(4)));
typedef float floatx4 __attribute__((ext_vector_type(4)));
typedef float floatx16 __attribute__((ext_vector_type(16)));

__device__ inline short f2bf(float x) {
    unsigned u = __float_as_uint(x);
    return (short)((u + 0x7fffu + ((u >> 16) & 1u)) >> 16);
}

#if __has_builtin(__builtin_amdgcn_cvt_pk_bf16_f32)
typedef __bf16 bf16x2_t __attribute__((ext_vector_type(2)));
__device__ inline unsigned pk2(float a, float b) {
    bf16x2_t v = __builtin_amdgcn_cvt_pk_bf16_f32(a, b);
    return __builtin_bit_cast(unsigned, v);
}
#else
__device__ inline unsigned pk2(float a, float b) {
    unsigned ua = __float_as_uint(a), ub = __float_as_uint(b);
    ua = (ua + 0x7fffu + ((ua >> 16) & 1u)) >> 16;
    ub = (ub + 0x7fffu + ((ub >> 16) & 1u)) & 0xffff0000u;
    return ua | ub;
}
#endif

// softplus, input pre-scaled xs = x*log2e. ONE transcendental:
// softplus = ln2*(max(xs,0) + log2(1+2^-|xs|)); log2(1+t) ~= t*(C0 + t*(C1 + t*C2)), t in (0,1]
// C0=log2e anchors t->0; poly exact at t=1; max abs err ~0.0024 (below bf16 quantization).
__device__ inline float sp2(float xs) {
    float m = fmaxf(xs, 0.f);
#if __has_builtin(__builtin_amdgcn_exp2f)
    float t = __builtin_amdgcn_exp2f(-fabsf(xs));
#else
    float t = exp2f(-fabsf(xs));
#endif
    float q = fmaf(t, fmaf(t, 0.2057f, -0.6484f), 1.4426950f);
    return fmaf(t, q, m) * LN2;
}

// bf16-as-bits -> f32
__device__ inline float blo(unsigned d) { return __uint_as_float(d << 16); }
__device__ inline float bhif(unsigned d) { return __uint_as_float(d & 0xffff0000u); }

// b64-pair load of a 16B fragment (8B-aligned addresses)
__device__ inline short8 ld8(const short* p) {
    short4v lo = *(const short4v*)p;
    short4v hi = *(const short4v*)(p + 4);
    return short8{lo[0], lo[1], lo[2], lo[3], hi[0], hi[1], hi[2], hi[3]};
}

// W1 as A-frag of W1^T for 32x32x16 (scaled by log2e):
//   frag(ks,nt,lane,j) = W1[16ks + 8*(lane>>5) + j][32nt + (lane&31)] * log2e
// W2 as A-frag of W2^T for 16x16x32 (N pad 16), plain.
// scal: [0:128) ib1s [128:256) fb1s [256:1024) iW0s [1024:1152) ib0s
//       [1152:1664) fW0s [1664:1792) fb0s   (all *log2e)
__global__ void prep_weights(const float* __restrict__ iW1, const float* __restrict__ fW1,
                             const float* __restrict__ iW2, const float* __restrict__ fW2,
                             const float* __restrict__ ib1, const float* __restrict__ fb1,
                             const float* __restrict__ iW0, const float* __restrict__ ib0,
                             const float* __restrict__ fW0, const float* __restrict__ fb0,
                             short* __restrict__ W1Fi, short* __restrict__ W1Ff,
                             short* __restrict__ W2Fi, short* __restrict__ W2Ff,
                             float* __restrict__ scal) {
    int t = blockIdx.x * blockDim.x + threadIdx.x;
    int stride = gridDim.x * blockDim.x;
    for (int fidx = t; fidx < 16384; fidx += stride) {
        int j = fidx & 7, lane = (fidx >> 3) & 63, nt = (fidx >> 9) & 3, ks = fidx >> 11;
        int k = 16 * ks + ((lane >> 5) << 3) + j;
        int n = 32 * nt + (lane & 31);
        W1Fi[fidx] = f2bf(iW1[k * H + n] * LOG2E);
        W1Ff[fidx] = f2bf(fW1[k * H + n] * LOG2E);
    }
    for (int fidx = t; fidx < 2048; fidx += stride) {
        int j = fidx & 7, lane = (fidx >> 3) & 63, ks = fidx >> 9;
        int k = 32 * ks + ((lane >> 4) << 3) + j;
        int n = lane & 15;
        W2Fi[fidx] = (n < 4) ? f2bf(iW2[k * 4 + n]) : (short)0;
        W2Ff[fidx] = (n < 4) ? f2bf(fW2[k * 4 + n]) : (short)0;
    }
    if (t < 128) {
        scal[t] = ib1[t] * LOG2E;
        scal[128 + t] = fb1[t] * LOG2E;
        scal[1024 + t] = ib0[t] * LOG2E;
        scal[1664 + t] = fb0[t] * LOG2E;
    }
    if (t < 768) scal[256 + t] = iW0[t] * LOG2E;
    if (t < 512) scal[1152 + t] = fW0[t] * LOG2E;
}

// One system per 512-thread block. Wave w: nt=w&3 (32 hidden cols), mhalf=w>>2 (2 row-tiles).
__global__ __launch_bounds__(512, 8) void fused_kernel(
    const float* __restrict__ z,
    const float* __restrict__ ib2, const float* __restrict__ fb2,
    const short* __restrict__ W1Fi, const short* __restrict__ W2Fi,
    const short* __restrict__ W1Ff, const short* __restrict__ W2Ff,
    const float* __restrict__ scal, float* __restrict__ out) {
    __shared__ __align__(16) short h0s[MROWS * LDH];      // 33792 B; h1 in place
    __shared__ __align__(16) short uwsb[2 * BB * UST];    // u | w as bf16; outs overlays
    __shared__ __align__(16) float4 zs4[BB];
    short* usb = uwsb;
    short* wsb = uwsb + BB * UST;
    float* outs = (float*)uwsb;                           // 448 f32, dead after stage B

    int n = blockIdx.x;
    int tid = threadIdx.x, lane = tid & 63, wave = tid >> 6;
    int c31 = lane & 31, halfk = lane >> 5;
    int ntw = wave & 3, mhalf = wave >> 2;

    if (tid < BB) zs4[tid] = ((const float4*)z)[n * BB + tid];
    __syncthreads();

    // Stage A: u_i, w_j as bf16 (log2 domain). preact(i,j) = u_i + w_j.
    {
        const float* iW0s = scal + 256;
        for (int u = tid; u < 640; u += 512) {
            int b = u >> 6, c2 = (u & 63) * 2;
            float4 zb = zs4[b];
            float2 p0 = *(const float2*)(iW0s + c2);
            float2 p1 = *(const float2*)(iW0s + 128 + c2);
            float2 p2 = *(const float2*)(iW0s + 256 + c2);
            float2 p3 = *(const float2*)(iW0s + 384 + c2);
            float2 p4 = *(const float2*)(iW0s + 512 + c2);
            float2 p5 = *(const float2*)(iW0s + 640 + c2);
            float2 pb = *(const float2*)(scal + 1024 + c2);
            float s0 = zb.x * p0.x + zb.y * p1.x;
            float s1 = zb.x * p0.y + zb.y * p1.y;
            float u0 = pb.x + s0 + zb.z * p2.x + zb.w * p3.x;
            float u1 = pb.y + s1 + zb.z * p2.y + zb.w * p3.y;
            float w0 = -s0 + zb.z * p4.x + zb.w * p5.x;
            float w1 = -s1 + zb.z * p4.y + zb.w * p5.y;
            *(unsigned*)(usb + b * UST + c2) = pk2(u0, u1);
            *(unsigned*)(wsb + b * UST + c2) = pk2(w0, w1);
        }
    }
    // Stage A2: self h0 rows 96..105 (4 cols/lane)
    if (tid < 320) {
        int b = tid >> 5, c4 = (tid & 31) * 4;
        const float* fW0s = scal + 1152;
        float4 zb = zs4[b];
        float4 q0 = *(const float4*)(fW0s + c4);
        float4 q1 = *(const float4*)(fW0s + 128 + c4);
        float4 q2 = *(const float4*)(fW0s + 256 + c4);
        float4 q3 = *(const float4*)(fW0s + 384 + c4);
        float4 qb = *(const float4*)(scal + 1664 + c4);
        float a0 = qb.x + zb.x * q0.x + zb.y * q1.x + zb.z * q2.x + zb.w * q3.x;
        float a1 = qb.y + zb.x * q0.y + zb.y * q1.y + zb.z * q2.y + zb.w * q3.y;
        float a2 = qb.z + zb.x * q0.z + zb.y * q1.z + zb.z * q2.z + zb.w * q3.z;
        float a3 = qb.w + zb.x * q0.w + zb.y * q1.w + zb.z * q2.w + zb.w * q3.w;
        uint2 pk;
        pk.x = pk2(sp2(a0), sp2(a1));
        pk.y = pk2(sp2(a2), sp2(a3));
        *(uint2*)(h0s + (96 + b) * LDH + c4) = pk;
    }
    // Zero pad rows 106..127 (22 rows x 33 uint2)
    for (int t = tid; t < 726; t += 512) {
        int r = 106 + t / 33, d2 = (t % 33) * 4;
        *(uint2*)(h0s + r * LDH + d2) = uint2{0u, 0u};
    }
    __syncthreads();

    // Stage B: pair h0 rows 0..95 (8 cols/lane; rows 90..95 zero)
    {
        int m0 = tid >> 4, c8 = (tid & 15) * 8;
#pragma unroll
        for (int t = 0; t < 3; ++t) {
            int m = m0 + 32 * t;
            uint2 o0 = {0u, 0u}, o1 = {0u, 0u};
            if (m < PAIRS) {
                int i = (m * 57) >> 9;   // m/9 for m<96
                int s = m - 9 * i;
                int j = s + (s >= i);
                uint4 uu = *(const uint4*)(usb + i * UST + c8);
                uint4 ww = *(const uint4*)(wsb + j * UST + c8);
                float x0 = blo(uu.x) + blo(ww.x), x1 = bhif(uu.x) + bhif(ww.x);
                float x2 = blo(uu.y) + blo(ww.y), x3 = bhif(uu.y) + bhif(ww.y);
                float x4 = blo(uu.z) + blo(ww.z), x5 = bhif(uu.z) + bhif(ww.z);
                float x6 = blo(uu.w) + blo(ww.w), x7 = bhif(uu.w) + bhif(ww.w);
                o0.x = pk2(sp2(x0), sp2(x1));
                o0.y = pk2(sp2(x2), sp2(x3));
                o1.x = pk2(sp2(x4), sp2(x5));
                o1.y = pk2(sp2(x6), sp2(x7));
            }
            *(uint2*)(h0s + m * LDH + c8) = o0;
            *(uint2*)(h0s + m * LDH + c8 + 4) = o1;
        }
    }
    __syncthreads();

    // Layer1: D = W1^T * h0^T via 32x32x16; A-frags streamed from global (L1) with +1 prefetch.
    int hb = 32 * ntw + 4 * halfk;
    floatx16 acc0, acc1;
    {
        const float* blo_ = scal;                          // int b1 (tiles 0..2)
        const float* bhi_ = mhalf ? (scal + 128) : scal;   // tile1 int / tile3 self
#pragma unroll
        for (int g = 0; g < 4; ++g) {
            float4 v0 = *(const float4*)(blo_ + hb + 8 * g);
            float4 v1 = *(const float4*)(bhi_ + hb + 8 * g);
            acc0[4 * g + 0] = v0.x; acc0[4 * g + 1] = v0.y;
            acc0[4 * g + 2] = v0.z; acc0[4 * g + 3] = v0.w;
            acc1[4 * g + 0] = v1.x; acc1[4 * g + 1] = v1.y;
            acc1[4 * g + 2] = v1.z; acc1[4 * g + 3] = v1.w;
        }
    }
    int rowA = 64 * mhalf + c31;
    int rowB = rowA + 32;
    {
        const short* WA = W1Fi + (ntw * 64 + lane) * 8;    // +2048 shorts per ks
        short8 a_cur = *(const short8*)WA;
#pragma unroll
        for (int ks = 0; ks < 8; ++ks) {
            short8 a_nxt = a_cur;
            if (ks < 7) a_nxt = *(const short8*)(WA + (ks + 1) * 2048);
            short8 bf = ld8(h0s + rowA * LDH + 16 * ks + 8 * halfk);
            acc0 = __builtin_amdgcn_mfma_f32_32x32x16_bf16(a_cur, bf, acc0, 0, 0, 0);
            a_cur = a_nxt;
        }
    }
    {
        const short* WB = (mhalf ? W1Ff : W1Fi) + (ntw * 64 + lane) * 8;
        short8 a_cur = *(const short8*)WB;
#pragma unroll
        for (int ks = 0; ks < 8; ++ks) {
            short8 a_nxt = a_cur;
            if (ks < 7) a_nxt = *(const short8*)(WB + (ks + 1) * 2048);
            short8 bf = ld8(h0s + rowB * LDH + 16 * ks + 8 * halfk);
            acc1 = __builtin_amdgcn_mfma_f32_32x32x16_bf16(a_cur, bf, acc1, 0, 0, 0);
            a_cur = a_nxt;
        }
    }
    __syncthreads();   // all layer1 reads done -> in-place h1 writes safe

    // Layer1 epilogue: h1 = softplus(acc) in place
#pragma unroll
    for (int g = 0; g < 4; ++g) {
        uint2 pa, pb;
        pa.x = pk2(sp2(acc0[4 * g + 0]), sp2(acc0[4 * g + 1]));
        pa.y = pk2(sp2(acc0[4 * g + 2]), sp2(acc0[4 * g + 3]));
        pb.x = pk2(sp2(acc1[4 * g + 0]), sp2(acc1[4 * g + 1]));
        pb.y = pk2(sp2(acc1[4 * g + 2]), sp2(acc1[4 * g + 3]));
        *(uint2*)(h0s + rowA * LDH + 32 * ntw + 8 * g + 4 * halfk) = pa;
        *(uint2*)(h0s + rowB * LDH + 32 * ntw + 8 * g + 4 * halfk) = pb;
    }
    __syncthreads();

    // Layer2 (16x16x32 transposed): wave w -> 16-row tile w (rows 0..111); quad0 lanes own one row
    {
        int rit = lane & 15, quad = lane >> 4;
        if (wave < 7) {
            const short* W2 = (wave == 6) ? W2Ff : W2Fi;
            const float* b2 = (wave == 6) ? fb2 : ib2;
            floatx4 a = {0.f, 0.f, 0.f, 0.f};
            if (quad == 0) {
                float4 bbv = *(const float4*)b2;
                a = floatx4{bbv.x, bbv.y, bbv.z, bbv.w};
            }
#pragma unroll
            for (int ks = 0; ks < 4; ++ks) {
                short8 w2v = *(const short8*)(W2 + (ks * 64 + lane) * 8);
                short8 bf = ld8(h0s + (16 * wave + rit) * LDH + 32 * ks + quad * 8);
                a = __builtin_amdgcn_mfma_f32_16x16x32_bf16(w2v, bf, a, 0, 0, 0);
            }
            if (quad == 0) {
                float4 o = {a[0], a[1], a[2], a[3]};
                *(float4*)(outs + (16 * wave + rit) * 4) = o;
            }
        }
    }
    __syncthreads();

    // Final: out[body i] = self_row(96+i) + sum of its 9 pair rows
    if (tid < BB * 4) {
        int i = tid >> 2, c = tid & 3;
        float s = outs[(96 + i) * 4 + c];
#pragma unroll
        for (int p = 0; p < 9; ++p) s += outs[(9 * i + p) * 4 + c];
        out[(n * BB + i) * 4 + c] = s;
    }
}

extern "C" void kernel_launch(void* const* d_in, const int* in_sizes, int n_in,
                              void* d_out, int out_size, void* d_ws, size_t ws_size,
                              hipStream_t stream) {
    const float* z   = (const float*)d_in[0];
    const float* fW0 = (const float*)d_in[1];
    const float* fb0 = (const float*)d_in[2];
    const float* fW1 = (const float*)d_in[3];
    const float* fb1 = (const float*)d_in[4];
    const float* fW2 = (const float*)d_in[5];
    const float* fb2 = (const float*)d_in[6];
    const float* iW0 = (const float*)d_in[7];
    const float* ib0 = (const float*)d_in[8];
    const float* iW1 = (const float*)d_in[9];
    const float* ib1 = (const float*)d_in[10];
    const float* iW2 = (const float*)d_in[11];
    const float* ib2 = (const float*)d_in[12];
    float* out = (float*)d_out;

    short* wsS = (short*)d_ws;
    short* W1Fi = wsS;            // 16384 bf16
    short* W1Ff = wsS + 16384;    // 16384 bf16
    short* W2Fi = wsS + 32768;    // 2048 bf16
    short* W2Ff = wsS + 34816;    // 2048 bf16
    float* scal = (float*)(wsS + 36864);   // 1792 f32

    int NB = in_sizes[0] / (2 * NDIM);
    int Nsys = NB / BB;

    hipLaunchKernelGGL(prep_weights, dim3(128), dim3(256), 0, stream,
                       iW1, fW1, iW2, fW2, ib1, fb1, iW0, ib0, fW0, fb0,
                       W1Fi, W1Ff, W2Fi, W2Ff, scal);
    hipLaunchKernelGGL(fused_kernel, dim3(Nsys), dim3(512), 0, stream,
                       z, ib2, fb2, W1Fi, W2Fi, W1Ff, W2Ff, scal, out);
}

// Round 7
// 184.355 us; speedup vs baseline: 1.0360x; 1.0360x over previous
//
#include <hip/hip_runtime.h>
#include <hip/hip_bf16.h>

#define NDIM 2
#define BB 10
#define H 128
#define PAIRS 90
#define MROWS 128
#define LDH 136      // h0/h1 stride in shorts: 272B, 16B-aligned rows -> real ds_read_b128
#define UST 136      // u/w bf16 stride in shorts
#define LOG2E 1.4426950408889634f
#define LN2   0.6931471805599453f

typedef short short8 __attribute__((ext_vector_type(8)));
typedef float floatx4 __attribute__((ext_vector_type(4)));
typedef float floatx16 __attribute__((ext_vector_type(16)));

__device__ inline short f2bf(float x) {
    unsigned u = __float_as_uint(x);
    return (short)((u + 0x7fffu + ((u >> 16) & 1u)) >> 16);
}

#if __has_builtin(__builtin_amdgcn_cvt_pk_bf16_f32)
typedef __bf16 bf16x2_t __attribute__((ext_vector_type(2)));
__device__ inline unsigned pk2(float a, float b) {
    bf16x2_t v = __builtin_amdgcn_cvt_pk_bf16_f32(a, b);
    return __builtin_bit_cast(unsigned, v);
}
#else
__device__ inline unsigned pk2(float a, float b) {
    unsigned ua = __float_as_uint(a), ub = __float_as_uint(b);
    ua = (ua + 0x7fffu + ((ua >> 16) & 1u)) >> 16;
    ub = (ub + 0x7fffu + ((ub >> 16) & 1u)) & 0xffff0000u;
    return ua | ub;
}
#endif

// softplus, input pre-scaled xs = x*log2e. ONE transcendental:
// softplus = ln2*(max(xs,0) + log2(1+2^-|xs|)); log2(1+t) ~= t*(C0 + t*(C1 + t*C2))
// C0=log2e anchors t->0; exact at t=1; max abs err ~0.0024 (below bf16 quantization).
__device__ inline float sp2(float xs) {
    float m = fmaxf(xs, 0.f);
#if __has_builtin(__builtin_amdgcn_exp2f)
    float t = __builtin_amdgcn_exp2f(-fabsf(xs));
#else
    float t = exp2f(-fabsf(xs));
#endif
    float q = fmaf(t, fmaf(t, 0.2057f, -0.6484f), 1.4426950f);
    return fmaf(t, q, m) * LN2;
}

// bf16-as-bits -> f32
__device__ inline float blo(unsigned d) { return __uint_as_float(d << 16); }
__device__ inline float bhif(unsigned d) { return __uint_as_float(d & 0xffff0000u); }

// W1 as A-frag of W1^T for 32x32x16 (scaled by log2e):
//   frag(ks,nt,lane,j) = W1[16ks + 8*(lane>>5) + j][32nt + (lane&31)] * log2e
// W2 as A-frag of W2^T for 16x16x32 (N pad 16), plain.
// scal: [0:128) ib1s [128:256) fb1s [256:1024) iW0s [1024:1152) ib0s
//       [1152:1664) fW0s [1664:1792) fb0s   (all *log2e)
__global__ void prep_weights(const float* __restrict__ iW1, const float* __restrict__ fW1,
                             const float* __restrict__ iW2, const float* __restrict__ fW2,
                             const float* __restrict__ ib1, const float* __restrict__ fb1,
                             const float* __restrict__ iW0, const float* __restrict__ ib0,
                             const float* __restrict__ fW0, const float* __restrict__ fb0,
                             short* __restrict__ W1Fi, short* __restrict__ W1Ff,
                             short* __restrict__ W2Fi, short* __restrict__ W2Ff,
                             float* __restrict__ scal) {
    int t = blockIdx.x * blockDim.x + threadIdx.x;
    int stride = gridDim.x * blockDim.x;
    for (int fidx = t; fidx < 16384; fidx += stride) {
        int j = fidx & 7, lane = (fidx >> 3) & 63, nt = (fidx >> 9) & 3, ks = fidx >> 11;
        int k = 16 * ks + ((lane >> 5) << 3) + j;
        int n = 32 * nt + (lane & 31);
        W1Fi[fidx] = f2bf(iW1[k * H + n] * LOG2E);
        W1Ff[fidx] = f2bf(fW1[k * H + n] * LOG2E);
    }
    for (int fidx = t; fidx < 2048; fidx += stride) {
        int j = fidx & 7, lane = (fidx >> 3) & 63, ks = fidx >> 9;
        int k = 32 * ks + ((lane >> 4) << 3) + j;
        int n = lane & 15;
        W2Fi[fidx] = (n < 4) ? f2bf(iW2[k * 4 + n]) : (short)0;
        W2Ff[fidx] = (n < 4) ? f2bf(fW2[k * 4 + n]) : (short)0;
    }
    if (t < 128) {
        scal[t] = ib1[t] * LOG2E;
        scal[128 + t] = fb1[t] * LOG2E;
        scal[1024 + t] = ib0[t] * LOG2E;
        scal[1664 + t] = fb0[t] * LOG2E;
    }
    if (t < 768) scal[256 + t] = iW0[t] * LOG2E;
    if (t < 512) scal[1152 + t] = fW0[t] * LOG2E;
}

// One system per 512-thread block. Wave w: nt=w&3 (32 hidden cols), mhalf=w>>2 (2 row-tiles).
__global__ __launch_bounds__(512, 6) void fused_kernel(
    const float* __restrict__ z,
    const float* __restrict__ ib2, const float* __restrict__ fb2,
    const short* __restrict__ W1Fi, const short* __restrict__ W2Fi,
    const short* __restrict__ W1Ff, const short* __restrict__ W2Ff,
    const float* __restrict__ scal, float* __restrict__ out) {
    __shared__ __align__(16) short h0s[MROWS * LDH];      // 34816 B; h1 in place
    __shared__ __align__(16) short uwsb[2 * BB * UST];    // u | w as bf16; outs overlays
    __shared__ __align__(16) float4 zs4[BB];
    short* usb = uwsb;
    short* wsb = uwsb + BB * UST;
    float* outs = (float*)uwsb;                           // 448 f32, dead after stage B

    int n = blockIdx.x;
    int tid = threadIdx.x, lane = tid & 63, wave = tid >> 6;
    int c31 = lane & 31, halfk = lane >> 5;
    int ntw = wave & 3, mhalf = wave >> 2;

    // Preload layer1 A-frags in registers (int weights for the first row-tile)
    short8 af[8];
#pragma unroll
    for (int ks = 0; ks < 8; ++ks)
        af[ks] = *(const short8*)(W1Fi + ((ks * 4 + ntw) * 64 + lane) * 8);

    if (tid < BB) zs4[tid] = ((const float4*)z)[n * BB + tid];
    __syncthreads();

    // Stage A: u_i, w_j as bf16 (log2 domain). preact(i,j) = u_i + w_j.
    {
        const float* iW0s = scal + 256;
        for (int u = tid; u < 640; u += 512) {
            int b = u >> 6, c2 = (u & 63) * 2;
            float4 zb = zs4[b];
            float2 p0 = *(const float2*)(iW0s + c2);
            float2 p1 = *(const float2*)(iW0s + 128 + c2);
            float2 p2 = *(const float2*)(iW0s + 256 + c2);
            float2 p3 = *(const float2*)(iW0s + 384 + c2);
            float2 p4 = *(const float2*)(iW0s + 512 + c2);
            float2 p5 = *(const float2*)(iW0s + 640 + c2);
            float2 pb = *(const float2*)(scal + 1024 + c2);
            float s0 = zb.x * p0.x + zb.y * p1.x;
            float s1 = zb.x * p0.y + zb.y * p1.y;
            float u0 = pb.x + s0 + zb.z * p2.x + zb.w * p3.x;
            float u1 = pb.y + s1 + zb.z * p2.y + zb.w * p3.y;
            float w0 = -s0 + zb.z * p4.x + zb.w * p5.x;
            float w1 = -s1 + zb.z * p4.y + zb.w * p5.y;
            *(unsigned*)(usb + b * UST + c2) = pk2(u0, u1);
            *(unsigned*)(wsb + b * UST + c2) = pk2(w0, w1);
        }
    }
    // Stage A2: self h0 rows 96..105 (4 cols/lane)
    if (tid < 320) {
        int b = tid >> 5, c4 = (tid & 31) * 4;
        const float* fW0s = scal + 1152;
        float4 zb = zs4[b];
        float4 q0 = *(const float4*)(fW0s + c4);
        float4 q1 = *(const float4*)(fW0s + 128 + c4);
        float4 q2 = *(const float4*)(fW0s + 256 + c4);
        float4 q3 = *(const float4*)(fW0s + 384 + c4);
        float4 qb = *(const float4*)(scal + 1664 + c4);
        float a0 = qb.x + zb.x * q0.x + zb.y * q1.x + zb.z * q2.x + zb.w * q3.x;
        float a1 = qb.y + zb.x * q0.y + zb.y * q1.y + zb.z * q2.y + zb.w * q3.y;
        float a2 = qb.z + zb.x * q0.z + zb.y * q1.z + zb.z * q2.z + zb.w * q3.z;
        float a3 = qb.w + zb.x * q0.w + zb.y * q1.w + zb.z * q2.w + zb.w * q3.w;
        uint2 pk;
        pk.x = pk2(sp2(a0), sp2(a1));
        pk.y = pk2(sp2(a2), sp2(a3));
        *(uint2*)(h0s + (96 + b) * LDH + c4) = pk;
    }
    // Zero pad rows 106..127 (22 rows x 16 uint4)
    if (tid < 352) {
        int r = 106 + (tid >> 4), c8 = (tid & 15) * 8;
        *(uint4*)(h0s + r * LDH + c8) = uint4{0u, 0u, 0u, 0u};
    }
    __syncthreads();

    // Stage B: pair h0 rows 0..95 (8 cols/lane; rows 90..95 zero)
    {
        int m0 = tid >> 4, c8 = (tid & 15) * 8;
#pragma unroll
        for (int t = 0; t < 3; ++t) {
            int m = m0 + 32 * t;
            uint4 o = {0u, 0u, 0u, 0u};
            if (m < PAIRS) {
                int i = (m * 57) >> 9;   // m/9 for m<96
                int s = m - 9 * i;
                int j = s + (s >= i);
                uint4 uu = *(const uint4*)(usb + i * UST + c8);
                uint4 ww = *(const uint4*)(wsb + j * UST + c8);
                float x0 = blo(uu.x) + blo(ww.x), x1 = bhif(uu.x) + bhif(ww.x);
                float x2 = blo(uu.y) + blo(ww.y), x3 = bhif(uu.y) + bhif(ww.y);
                float x4 = blo(uu.z) + blo(ww.z), x5 = bhif(uu.z) + bhif(ww.z);
                float x6 = blo(uu.w) + blo(ww.w), x7 = bhif(uu.w) + bhif(ww.w);
                o.x = pk2(sp2(x0), sp2(x1));
                o.y = pk2(sp2(x2), sp2(x3));
                o.z = pk2(sp2(x4), sp2(x5));
                o.w = pk2(sp2(x6), sp2(x7));
            }
            *(uint4*)(h0s + m * LDH + c8) = o;
        }
    }
    __syncthreads();

    // Layer1: D = W1^T * h0^T via 32x32x16; af[] in registers.
    int hb = 32 * ntw + 4 * halfk;
    floatx16 acc0, acc1;
    {
        const float* blo_ = scal;                          // int b1 (tiles 0..2)
        const float* bhi_ = mhalf ? (scal + 128) : scal;   // tile1 int / tile3 self
#pragma unroll
        for (int g = 0; g < 4; ++g) {
            float4 v0 = *(const float4*)(blo_ + hb + 8 * g);
            float4 v1 = *(const float4*)(bhi_ + hb + 8 * g);
            acc0[4 * g + 0] = v0.x; acc0[4 * g + 1] = v0.y;
            acc0[4 * g + 2] = v0.z; acc0[4 * g + 3] = v0.w;
            acc1[4 * g + 0] = v1.x; acc1[4 * g + 1] = v1.y;
            acc1[4 * g + 2] = v1.z; acc1[4 * g + 3] = v1.w;
        }
    }
    int rowA = 64 * mhalf + c31;
    int rowB = rowA + 32;
#pragma unroll
    for (int ks = 0; ks < 8; ++ks) {
        short8 bf = *(const short8*)(h0s + rowA * LDH + 16 * ks + 8 * halfk);
        acc0 = __builtin_amdgcn_mfma_f32_32x32x16_bf16(af[ks], bf, acc0, 0, 0, 0);
    }
    if (mhalf) {   // wave-uniform: second row-tile is the self tile -> swap to fW1 frags
#pragma unroll
        for (int ks = 0; ks < 8; ++ks)
            af[ks] = *(const short8*)(W1Ff + ((ks * 4 + ntw) * 64 + lane) * 8);
    }
#pragma unroll
    for (int ks = 0; ks < 8; ++ks) {
        short8 bf = *(const short8*)(h0s + rowB * LDH + 16 * ks + 8 * halfk);
        acc1 = __builtin_amdgcn_mfma_f32_32x32x16_bf16(af[ks], bf, acc1, 0, 0, 0);
    }
    __syncthreads();   // all layer1 reads done -> in-place h1 writes safe

    // Layer1 epilogue: h1 = softplus(acc) in place
#pragma unroll
    for (int g = 0; g < 4; ++g) {
        uint2 pa, pb;
        pa.x = pk2(sp2(acc0[4 * g + 0]), sp2(acc0[4 * g + 1]));
        pa.y = pk2(sp2(acc0[4 * g + 2]), sp2(acc0[4 * g + 3]));
        pb.x = pk2(sp2(acc1[4 * g + 0]), sp2(acc1[4 * g + 1]));
        pb.y = pk2(sp2(acc1[4 * g + 2]), sp2(acc1[4 * g + 3]));
        *(uint2*)(h0s + rowA * LDH + 32 * ntw + 8 * g + 4 * halfk) = pa;
        *(uint2*)(h0s + rowB * LDH + 32 * ntw + 8 * g + 4 * halfk) = pb;
    }
    __syncthreads();

    // Layer2 (16x16x32 transposed): wave w -> 16-row tile w; quad0 lanes own one row
    {
        int rit = lane & 15, quad = lane >> 4;
        if (wave < 7) {
            const short* W2 = (wave == 6) ? W2Ff : W2Fi;
            const float* b2 = (wave == 6) ? fb2 : ib2;
            floatx4 a = {0.f, 0.f, 0.f, 0.f};
            if (quad == 0) {
                float4 bbv = *(const float4*)b2;
                a = floatx4{bbv.x, bbv.y, bbv.z, bbv.w};
            }
#pragma unroll
            for (int ks = 0; ks < 4; ++ks) {
                short8 w2v = *(const short8*)(W2 + (ks * 64 + lane) * 8);
                short8 bf = *(const short8*)(h0s + (16 * wave + rit) * LDH + 32 * ks + quad * 8);
                a = __builtin_amdgcn_mfma_f32_16x16x32_bf16(w2v, bf, a, 0, 0, 0);
            }
            if (quad == 0) {
                float4 o = {a[0], a[1], a[2], a[3]};
                *(float4*)(outs + (16 * wave + rit) * 4) = o;
            }
        }
    }
    __syncthreads();

    // Final: out[body i] = self_row(96+i) + sum of its 9 pair rows
    if (tid < BB * 4) {
        int i = tid >> 2, c = tid & 3;
        float s = outs[(96 + i) * 4 + c];
#pragma unroll
        for (int p = 0; p < 9; ++p) s += outs[(9 * i + p) * 4 + c];
        out[(n * BB + i) * 4 + c] = s;
    }
}

extern "C" void kernel_launch(void* const* d_in, const int* in_sizes, int n_in,
                              void* d_out, int out_size, void* d_ws, size_t ws_size,
                              hipStream_t stream) {
    const float* z   = (const float*)d_in[0];
    const float* fW0 = (const float*)d_in[1];
    const float* fb0 = (const float*)d_in[2];
    const float* fW1 = (const float*)d_in[3];
    const float* fb1 = (const float*)d_in[4];
    const float* fW2 = (const float*)d_in[5];
    const float* fb2 = (const float*)d_in[6];
    const float* iW0 = (const float*)d_in[7];
    const float* ib0 = (const float*)d_in[8];
    const float* iW1 = (const float*)d_in[9];
    const float* ib1 = (const float*)d_in[10];
    const float* iW2 = (const float*)d_in[11];
    const float* ib2 = (const float*)d_in[12];
    float* out = (float*)d_out;

    short* wsS = (short*)d_ws;
    short* W1Fi = wsS;            // 16384 bf16
    short* W1Ff = wsS + 16384;    // 16384 bf16
    short* W2Fi = wsS + 32768;    // 2048 bf16
    short* W2Ff = wsS + 34816;    // 2048 bf16
    float* scal = (float*)(wsS + 36864);   // 1792 f32

    int NB = in_sizes[0] / (2 * NDIM);
    int Nsys = NB / BB;

    hipLaunchKernelGGL(prep_weights, dim3(128), dim3(256), 0, stream,
                       iW1, fW1, iW2, fW2, ib1, fb1, iW0, ib0, fW0, fb0,
                       W1Fi, W1Ff, W2Fi, W2Ff, scal);
    hipLaunchKernelGGL(fused_kernel, dim3(Nsys), dim3(512), 0, stream,
                       z, ib2, fb2, W1Fi, W2Fi, W1Ff, W2Ff, scal, out);
}

// Round 8
// 180.985 us; speedup vs baseline: 1.0553x; 1.0186x over previous
//
#include <hip/hip_runtime.h>
#include <hip/hip_bf16.h>

#define NDIM 2
#define BB 10
#define H 128
#define PAIRS 90
#define MROWS 128
#define LDH 136      // h0/h1 stride in shorts: 272B, 16B-aligned rows -> ds_read_b128
#define USLD 132     // u/w f32 stride: 528B rows, 16B-aligned, breaks 4-row bank alignment
#define LOG2E 1.4426950408889634f
#define LN2   0.6931471805599453f

typedef short short8 __attribute__((ext_vector_type(8)));
typedef float floatx2 __attribute__((ext_vector_type(2)));
typedef float floatx4 __attribute__((ext_vector_type(4)));
typedef float floatx16 __attribute__((ext_vector_type(16)));

__device__ inline short f2bf(float x) {
    unsigned u = __float_as_uint(x);
    return (short)((u + 0x7fffu + ((u >> 16) & 1u)) >> 16);
}

#if __has_builtin(__builtin_amdgcn_cvt_pk_bf16_f32)
typedef __bf16 bf16x2_t __attribute__((ext_vector_type(2)));
__device__ inline unsigned pk2(float a, float b) {
    bf16x2_t v = __builtin_amdgcn_cvt_pk_bf16_f32(a, b);
    return __builtin_bit_cast(unsigned, v);
}
#else
__device__ inline unsigned pk2(float a, float b) {
    unsigned ua = __float_as_uint(a), ub = __float_as_uint(b);
    ua = (ua + 0x7fffu + ((ua >> 16) & 1u)) >> 16;
    ub = (ub + 0x7fffu + ((ub >> 16) & 1u)) & 0xffff0000u;
    return ua | ub;
}
#endif

__device__ inline float ex2(float x) {
#if __has_builtin(__builtin_amdgcn_exp2f)
    return __builtin_amdgcn_exp2f(x);
#else
    return exp2f(x);
#endif
}

// log2-domain softplus (NO ln2 scaling): input xs = x*log2e,
// g = max(xs,0) + log2(1+2^-|xs|),  log2(1+t) ~= t*(C0 + C1 t + C2 t^2)
// The ln2 is folded into the NEXT layer's weights (W1 plain, W2 *= ln2).
// float4 version: scalar max/min/exp per lane-elem, packed-f32 fma chain.
__device__ inline floatx4 sp4(floatx4 xs) {
    floatx4 m, t;
    m[0] = fmaxf(xs[0], 0.f); m[1] = fmaxf(xs[1], 0.f);
    m[2] = fmaxf(xs[2], 0.f); m[3] = fmaxf(xs[3], 0.f);
    t[0] = ex2(fminf(xs[0], -xs[0])); t[1] = ex2(fminf(xs[1], -xs[1]));
    t[2] = ex2(fminf(xs[2], -xs[2])); t[3] = ex2(fminf(xs[3], -xs[3]));
    floatx4 q = t * (t * 0.2057f - 0.6484f) + 1.4426950f;
    return t * q + m;
}

// W1 as A-frag of W1^T for 32x32x16, PLAIN (g carries 1/ln2):
//   frag(ks,nt,lane,j) = W1[16ks + 8*(lane>>5) + j][32nt + (lane&31)]
// W2 as A-frag of W2^T for 16x16x32 (N pad 16), scaled by LN2.
// scal: [0:128) ib1*log2e [128:256) fb1*log2e [256:1024) iW0*log2e
//       [1024:1152) ib0*log2e [1152:1664) fW0*log2e [1664:1792) fb0*log2e
__global__ void prep_weights(const float* __restrict__ iW1, const float* __restrict__ fW1,
                             const float* __restrict__ iW2, const float* __restrict__ fW2,
                             const float* __restrict__ ib1, const float* __restrict__ fb1,
                             const float* __restrict__ iW0, const float* __restrict__ ib0,
                             const float* __restrict__ fW0, const float* __restrict__ fb0,
                             short* __restrict__ W1Fi, short* __restrict__ W1Ff,
                             short* __restrict__ W2Fi, short* __restrict__ W2Ff,
                             float* __restrict__ scal) {
    int t = blockIdx.x * blockDim.x + threadIdx.x;
    int stride = gridDim.x * blockDim.x;
    for (int fidx = t; fidx < 16384; fidx += stride) {
        int j = fidx & 7, lane = (fidx >> 3) & 63, nt = (fidx >> 9) & 3, ks = fidx >> 11;
        int k = 16 * ks + ((lane >> 5) << 3) + j;
        int n = 32 * nt + (lane & 31);
        W1Fi[fidx] = f2bf(iW1[k * H + n]);
        W1Ff[fidx] = f2bf(fW1[k * H + n]);
    }
    for (int fidx = t; fidx < 2048; fidx += stride) {
        int j = fidx & 7, lane = (fidx >> 3) & 63, ks = fidx >> 9;
        int k = 32 * ks + ((lane >> 4) << 3) + j;
        int n = lane & 15;
        W2Fi[fidx] = (n < 4) ? f2bf(iW2[k * 4 + n] * LN2) : (short)0;
        W2Ff[fidx] = (n < 4) ? f2bf(fW2[k * 4 + n] * LN2) : (short)0;
    }
    if (t < 128) {
        scal[t] = ib1[t] * LOG2E;
        scal[128 + t] = fb1[t] * LOG2E;
        scal[1024 + t] = ib0[t] * LOG2E;
        scal[1664 + t] = fb0[t] * LOG2E;
    }
    if (t < 768) scal[256 + t] = iW0[t] * LOG2E;
    if (t < 512) scal[1152 + t] = fW0[t] * LOG2E;
}

// One system per 512-thread block. Wave w: nt=w&3 (32 hidden cols), mhalf=w>>2 (2 row-tiles).
__global__ __launch_bounds__(512, 6) void fused_kernel(
    const float* __restrict__ z,
    const float* __restrict__ ib2, const float* __restrict__ fb2,
    const short* __restrict__ W1Fi, const short* __restrict__ W2Fi,
    const short* __restrict__ W1Ff, const short* __restrict__ W2Ff,
    const float* __restrict__ scal, float* __restrict__ out) {
    __shared__ __align__(16) short h0s[MROWS * LDH];      // 34816 B; h1 in place
    __shared__ __align__(16) float uws[2 * BB * USLD];    // u | w f32; outs overlays
    __shared__ __align__(16) float4 zs4[BB];
    float* us   = uws;
    float* wss  = uws + BB * USLD;
    float* outs = uws;                                    // 448 f32, dead after stage B

    int n = blockIdx.x;
    int tid = threadIdx.x, lane = tid & 63, wave = tid >> 6;
    int c31 = lane & 31, halfk = lane >> 5;
    int ntw = wave & 3, mhalf = wave >> 2;

    // Preload layer1 A-frags in registers (int weights for the first row-tile)
    short8 af[8];
#pragma unroll
    for (int ks = 0; ks < 8; ++ks)
        af[ks] = *(const short8*)(W1Fi + ((ks * 4 + ntw) * 64 + lane) * 8);

    if (tid < BB) zs4[tid] = ((const float4*)z)[n * BB + tid];
    __syncthreads();

    // Stage A: u_i, w_j in f32 (log2 domain), float2 packed math
    {
        const float* iW0s = scal + 256;
        for (int u = tid; u < 640; u += 512) {
            int b = u >> 6, c2 = (u & 63) * 2;
            float4 zb = zs4[b];
            floatx2 p0 = *(const floatx2*)(iW0s + c2);
            floatx2 p1 = *(const floatx2*)(iW0s + 128 + c2);
            floatx2 p2 = *(const floatx2*)(iW0s + 256 + c2);
            floatx2 p3 = *(const floatx2*)(iW0s + 384 + c2);
            floatx2 p4 = *(const floatx2*)(iW0s + 512 + c2);
            floatx2 p5 = *(const floatx2*)(iW0s + 640 + c2);
            floatx2 pb = *(const floatx2*)(scal + 1024 + c2);
            floatx2 s = p0 * zb.x + p1 * zb.y;
            floatx2 uv = pb + s + p2 * zb.z + p3 * zb.w;
            floatx2 wv = p4 * zb.z + p5 * zb.w - s;
            *(floatx2*)(us + b * USLD + c2) = uv;
            *(floatx2*)(wss + b * USLD + c2) = wv;
        }
    }
    // Stage A2: self h0 rows 96..105 (4 cols/lane), float4 packed math
    if (tid < 320) {
        int b = tid >> 5, c4 = (tid & 31) * 4;
        const float* fW0s = scal + 1152;
        float4 zb = zs4[b];
        floatx4 q0 = *(const floatx4*)(fW0s + c4);
        floatx4 q1 = *(const floatx4*)(fW0s + 128 + c4);
        floatx4 q2 = *(const floatx4*)(fW0s + 256 + c4);
        floatx4 q3 = *(const floatx4*)(fW0s + 384 + c4);
        floatx4 qb = *(const floatx4*)(scal + 1664 + c4);
        floatx4 a = qb + q0 * zb.x + q1 * zb.y + q2 * zb.z + q3 * zb.w;
        floatx4 g = sp4(a);
        uint2 pk;
        pk.x = pk2(g[0], g[1]);
        pk.y = pk2(g[2], g[3]);
        *(uint2*)(h0s + (96 + b) * LDH + c4) = pk;
    }
    // Zero pad rows 106..127
    if (tid < 352) {
        int r = 106 + (tid >> 4), c8 = (tid & 15) * 8;
        *(uint4*)(h0s + r * LDH + c8) = uint4{0u, 0u, 0u, 0u};
    }
    __syncthreads();

    // Stage B: pair h0 rows 0..95 (8 cols/lane; rows 90..95 zero)
    {
        int m0 = tid >> 4, c8 = (tid & 15) * 8;
#pragma unroll
        for (int t = 0; t < 3; ++t) {
            int m = m0 + 32 * t;
            uint4 o = {0u, 0u, 0u, 0u};
            if (m < PAIRS) {
                int i = (m * 57) >> 9;   // m/9 for m<96
                int s = m - 9 * i;
                int j = s + (s >= i);
                floatx4 ua = *(const floatx4*)(us + i * USLD + c8);
                floatx4 ub = *(const floatx4*)(us + i * USLD + c8 + 4);
                floatx4 wa = *(const floatx4*)(wss + j * USLD + c8);
                floatx4 wb = *(const floatx4*)(wss + j * USLD + c8 + 4);
                floatx4 ga = sp4(ua + wa);
                floatx4 gb = sp4(ub + wb);
                o.x = pk2(ga[0], ga[1]);
                o.y = pk2(ga[2], ga[3]);
                o.z = pk2(gb[0], gb[1]);
                o.w = pk2(gb[2], gb[3]);
            }
            *(uint4*)(h0s + m * LDH + c8) = o;
        }
    }
    __syncthreads();

    // Layer1: D = W1^T * g0^T via 32x32x16; af[] in registers; acc init = b1*log2e
    int hb = 32 * ntw + 4 * halfk;
    floatx16 acc0, acc1;
    {
        const float* blo_ = scal;                          // int b1 (tiles 0..2)
        const float* bhi_ = mhalf ? (scal + 128) : scal;   // tile1 int / tile3 self
#pragma unroll
        for (int g = 0; g < 4; ++g) {
            float4 v0 = *(const float4*)(blo_ + hb + 8 * g);
            float4 v1 = *(const float4*)(bhi_ + hb + 8 * g);
            acc0[4 * g + 0] = v0.x; acc0[4 * g + 1] = v0.y;
            acc0[4 * g + 2] = v0.z; acc0[4 * g + 3] = v0.w;
            acc1[4 * g + 0] = v1.x; acc1[4 * g + 1] = v1.y;
            acc1[4 * g + 2] = v1.z; acc1[4 * g + 3] = v1.w;
        }
    }
    int rowA = 64 * mhalf + c31;
    int rowB = rowA + 32;
#pragma unroll
    for (int ks = 0; ks < 8; ++ks) {
        short8 bf = *(const short8*)(h0s + rowA * LDH + 16 * ks + 8 * halfk);
        acc0 = __builtin_amdgcn_mfma_f32_32x32x16_bf16(af[ks], bf, acc0, 0, 0, 0);
    }
    if (mhalf) {   // wave-uniform: second row-tile is the self tile -> swap to fW1 frags
#pragma unroll
        for (int ks = 0; ks < 8; ++ks)
            af[ks] = *(const short8*)(W1Ff + ((ks * 4 + ntw) * 64 + lane) * 8);
    }
#pragma unroll
    for (int ks = 0; ks < 8; ++ks) {
        short8 bf = *(const short8*)(h0s + rowB * LDH + 16 * ks + 8 * halfk);
        acc1 = __builtin_amdgcn_mfma_f32_32x32x16_bf16(af[ks], bf, acc1, 0, 0, 0);
    }
    __syncthreads();   // all layer1 reads done -> in-place h1 writes safe

    // Layer1 epilogue: g1 = log2-softplus(acc) in place (float4 packed)
#pragma unroll
    for (int g = 0; g < 4; ++g) {
        floatx4 v0 = {acc0[4 * g], acc0[4 * g + 1], acc0[4 * g + 2], acc0[4 * g + 3]};
        floatx4 v1 = {acc1[4 * g], acc1[4 * g + 1], acc1[4 * g + 2], acc1[4 * g + 3]};
        floatx4 r0 = sp4(v0);
        floatx4 r1 = sp4(v1);
        uint2 pa, pb;
        pa.x = pk2(r0[0], r0[1]); pa.y = pk2(r0[2], r0[3]);
        pb.x = pk2(r1[0], r1[1]); pb.y = pk2(r1[2], r1[3]);
        *(uint2*)(h0s + rowA * LDH + 32 * ntw + 8 * g + 4 * halfk) = pa;
        *(uint2*)(h0s + rowB * LDH + 32 * ntw + 8 * g + 4 * halfk) = pb;
    }
    __syncthreads();

    // Layer2 (16x16x32 transposed, W2 pre-scaled by ln2): wave w -> 16-row tile w
    {
        int rit = lane & 15, quad = lane >> 4;
        if (wave < 7) {
            const short* W2 = (wave == 6) ? W2Ff : W2Fi;
            const float* b2 = (wave == 6) ? fb2 : ib2;
            floatx4 a = {0.f, 0.f, 0.f, 0.f};
            if (quad == 0) {
                float4 bbv = *(const float4*)b2;
                a = floatx4{bbv.x, bbv.y, bbv.z, bbv.w};
            }
#pragma unroll
            for (int ks = 0; ks < 4; ++ks) {
                short8 w2v = *(const short8*)(W2 + (ks * 64 + lane) * 8);
                short8 bf = *(const short8*)(h0s + (16 * wave + rit) * LDH + 32 * ks + quad * 8);
                a = __builtin_amdgcn_mfma_f32_16x16x32_bf16(w2v, bf, a, 0, 0, 0);
            }
            if (quad == 0) {
                float4 o = {a[0], a[1], a[2], a[3]};
                *(float4*)(outs + (16 * wave + rit) * 4) = o;
            }
        }
    }
    __syncthreads();

    // Final: out[body i] = self_row(96+i) + sum of its 9 pair rows
    if (tid < BB * 4) {
        int i = tid >> 2, c = tid & 3;
        float s = outs[(96 + i) * 4 + c];
#pragma unroll
        for (int p = 0; p < 9; ++p) s += outs[(9 * i + p) * 4 + c];
        out[(n * BB + i) * 4 + c] = s;
    }
}

extern "C" void kernel_launch(void* const* d_in, const int* in_sizes, int n_in,
                              void* d_out, int out_size, void* d_ws, size_t ws_size,
                              hipStream_t stream) {
    const float* z   = (const float*)d_in[0];
    const float* fW0 = (const float*)d_in[1];
    const float* fb0 = (const float*)d_in[2];
    const float* fW1 = (const float*)d_in[3];
    const float* fb1 = (const float*)d_in[4];
    const float* fW2 = (const float*)d_in[5];
    const float* fb2 = (const float*)d_in[6];
    const float* iW0 = (const float*)d_in[7];
    const float* ib0 = (const float*)d_in[8];
    const float* iW1 = (const float*)d_in[9];
    const float* ib1 = (const float*)d_in[10];
    const float* iW2 = (const float*)d_in[11];
    const float* ib2 = (const float*)d_in[12];
    float* out = (float*)d_out;

    short* wsS = (short*)d_ws;
    short* W1Fi = wsS;            // 16384 bf16
    short* W1Ff = wsS + 16384;    // 16384 bf16
    short* W2Fi = wsS + 32768;    // 2048 bf16
    short* W2Ff = wsS + 34816;    // 2048 bf16
    float* scal = (float*)(wsS + 36864);   // 1792 f32

    int NB = in_sizes[0] / (2 * NDIM);
    int Nsys = NB / BB;

    hipLaunchKernelGGL(prep_weights, dim3(128), dim3(256), 0, stream,
                       iW1, fW1, iW2, fW2, ib1, fb1, iW0, ib0, fW0, fb0,
                       W1Fi, W1Ff, W2Fi, W2Ff, scal);
    hipLaunchKernelGGL(fused_kernel, dim3(Nsys), dim3(512), 0, stream,
                       z, ib2, fb2, W1Fi, W2Fi, W1Ff, W2Ff, scal, out);
}